// Round 2
// baseline (303.051 us; speedup 1.0000x reference)
//
#include <hip/hip_runtime.h>

#define T_LEN 1024

typedef _Float16 f16x8 __attribute__((ext_vector_type(8)));
typedef __fp16   fp16x2 __attribute__((ext_vector_type(2)));
typedef float    f32x4 __attribute__((ext_vector_type(4)));

// One wave (64 threads) per block; block owns 16 batch rows for all T steps.
// R1 lesson: ALL waves are resident (1024 waves / 1024 SIMDs), so wall time =
// T x single-wave per-step chain. TLP/occupancy does not help; splitting H
// across waves added LDS+barrier to the chain and regressed (434->492 cy/step).
// This round: keep R0 structure, shorten per-step trans occupancy.
//
// Recurrence in "r-space": h = 1 - 2r, r = 1/(exp2(t)+1), t = K*v, K = 2*log2(e).
// Substituting h into v = x*Wih + b + W_hh h:
//   t[c] = K*(x*Wih[c] + b[c] + rowsum(W_hh[c,:])) + sum_k (-2K*W_hh[c,k]) * r[k]
// so A-frag = -2K*W_hh (f16) and r recirculates directly as the B-fragment.
//   A-frag: A[m=lane&15][k=quad*8+j] = -2K*Whh[sigma(m)][k]
//   B-frag: B[k=quad*8+j][n=lane&15] = r[row n][k]
//   C-frag: col n=lane&15 (batch row), row m=quad*4+reg; sigma0(m)=8*(m>>2)+(m&3),
//   sigma1=sigma0+4 ==> lane's C outputs are exactly its own B slots next step.
//
// Per-step pipeline: MFMA -> v_exp_f32(acc) -> +1 -> NEWTON-RCP -> cvt_pkrtz -> B.
// exp stays HW (no cheaper substitute: poly = ~8 VALU ops >= 16cy trans cost).
// rcp replaced by bit-trick seed + 2 Newton iters: 6 full-rate VALU ops (12cy
// occupancy, ~24cy latency) vs ~16cy quarter-rate trans occupancy. Rel err
// ~6e-6 after 2 iters -- far below the f16 quantum, absmax unchanged.
__device__ __forceinline__ float nrcp(float d) {
    // d >= 1 always (d = exp2(t)+1), so no denormal/zero edge cases.
    float y = __builtin_bit_cast(float, 0x7EF311C3u - __builtin_bit_cast(unsigned int, d));
    y = y * fmaf(-d, y, 2.0f);   // Newton: y <- y*(2 - d*y)
    y = y * fmaf(-d, y, 2.0f);
    return y;
}

__global__ __launch_bounds__(64) void rnn_fused(
    const float* __restrict__ x,      // [B, T]
    const float* __restrict__ W_ih,   // [32,1]
    const float* __restrict__ W_hh,   // [32,32]
    const float* __restrict__ b_ih,   // [32]
    const float* __restrict__ b_hh,   // [32]
    const float* __restrict__ fc_w,   // [1,32]
    const float* __restrict__ fc_b,   // [1]
    float* __restrict__ out)          // [B]
{
    const int lane = threadIdx.x;
    const int n = lane & 15;   // batch row within tile (B-frag col / C col)
    const int q = lane >> 4;   // quad index

    const float K = 2.88539008177792681472f;   // 2*log2(e)

    // A fragments: -2K * W_hh rows (permuted by sigma), f16.
    const int c0row = 8 * (n >> 2) + (n & 3);
    const int c1row = c0row + 4;
    f16x8 a0, a1;
#pragma unroll
    for (int j = 0; j < 8; ++j) {
        a0[j] = (_Float16)(-2.0f * K * W_hh[c0row * 32 + q * 8 + j]);
        a1[j] = (_Float16)(-2.0f * K * W_hh[c1row * 32 + q * 8 + j]);
    }

    // This lane produces h-columns c = 8q + i (i = 0..7).
    // bias' = K*(b_ih + b_hh + rowsum(W_hh[c,:]))  (r-space fold)
    float wih[8], bias[8];
#pragma unroll
    for (int i = 0; i < 8; ++i) {
        int c = 8 * q + i;
        float rs = 0.0f;
        for (int k = 0; k < 32; ++k) rs += W_hh[c * 32 + k];
        wih[i]  = K * W_ih[c];
        bias[i] = K * (b_ih[c] + b_hh[c] + rs);
    }

    const float* xrow = x + (size_t)(blockIdx.x * 16 + n) * T_LEN;
    float4 xa = *(const float4*)xrow;   // t = 0..3 (4 lanes/row redundant -> broadcast)

    // B fragment holds r; h=0 <=> r=0.5
    f16x8 hb;
#pragma unroll
    for (int i = 0; i < 8; ++i) hb[i] = (_Float16)0.5f;

    for (int t4 = 0; t4 < T_LEN / 4; ++t4) {
        const int nt4 = (t4 < T_LEN / 4 - 1) ? t4 + 1 : t4;   // prefetch next x chunk
        float4 xn = *(const float4*)(xrow + (size_t)nt4 * 4);
#pragma unroll
        for (int p = 0; p < 4; ++p) {
            const float xt = (p == 0) ? xa.x : (p == 1) ? xa.y : (p == 2) ? xa.z : xa.w;
            f32x4 acc0, acc1;
#pragma unroll
            for (int i = 0; i < 4; ++i) {
                acc0[i] = fmaf(xt, wih[i],     bias[i]);   // C-init = K*(x*Wih + b + rowsum)
                acc1[i] = fmaf(xt, wih[4 + i], bias[4 + i]);
            }
            acc0 = __builtin_amdgcn_mfma_f32_16x16x32_f16(a0, hb, acc0, 0, 0, 0);
            acc1 = __builtin_amdgcn_mfma_f32_16x16x32_f16(a1, hb, acc1, 0, 0, 0);

            // 8 HW exps stream through the trans pipe; Newton rcps on the
            // full-rate VALU pipe (overlaps trans grind; shorter dep chain).
            float e0 = __builtin_amdgcn_exp2f(acc0[0]);
            float e1 = __builtin_amdgcn_exp2f(acc0[1]);
            float e2 = __builtin_amdgcn_exp2f(acc0[2]);
            float e3 = __builtin_amdgcn_exp2f(acc0[3]);
            float e4 = __builtin_amdgcn_exp2f(acc1[0]);
            float e5 = __builtin_amdgcn_exp2f(acc1[1]);
            float e6 = __builtin_amdgcn_exp2f(acc1[2]);
            float e7 = __builtin_amdgcn_exp2f(acc1[3]);
            float r0 = nrcp(e0 + 1.0f);
            float r1 = nrcp(e1 + 1.0f);
            float r2 = nrcp(e2 + 1.0f);
            float r3 = nrcp(e3 + 1.0f);
            float r4 = nrcp(e4 + 1.0f);
            float r5 = nrcp(e5 + 1.0f);
            float r6 = nrcp(e6 + 1.0f);
            float r7 = nrcp(e7 + 1.0f);

            // pack r pairs directly: 4 x v_cvt_pkrtz_f16_f32 (no final fma — r-space)
            struct H4 { fp16x2 p[4]; } hh;
            hh.p[0] = __builtin_amdgcn_cvt_pkrtz(r0, r1);
            hh.p[1] = __builtin_amdgcn_cvt_pkrtz(r2, r3);
            hh.p[2] = __builtin_amdgcn_cvt_pkrtz(r4, r5);
            hh.p[3] = __builtin_amdgcn_cvt_pkrtz(r6, r7);
            hb = __builtin_bit_cast(f16x8, hh);
        }
        xa = xn;
    }

    // Head: h = 1 - 2r; out[row] = sum_c h[c] * fc_w[c] + fc_b
    float part = 0.0f;
#pragma unroll
    for (int i = 0; i < 8; ++i) {
        float h = fmaf(-2.0f, (float)hb[i], 1.0f);
        part = fmaf(h, fc_w[8 * q + i], part);
    }
    part += __shfl_xor(part, 16);
    part += __shfl_xor(part, 32);
    if (q == 0) out[blockIdx.x * 16 + n] = part + fc_b[0];
}

extern "C" void kernel_launch(void* const* d_in, const int* in_sizes, int n_in,
                              void* d_out, int out_size, void* d_ws, size_t ws_size,
                              hipStream_t stream) {
    const float* x    = (const float*)d_in[0];
    const float* W_ih = (const float*)d_in[1];
    const float* W_hh = (const float*)d_in[2];
    const float* b_ih = (const float*)d_in[3];
    const float* b_hh = (const float*)d_in[4];
    const float* fc_w = (const float*)d_in[5];
    const float* fc_b = (const float*)d_in[6];
    float* out = (float*)d_out;

    const int B = in_sizes[0] / T_LEN;   // 16384
    rnn_fused<<<B / 16, 64, 0, stream>>>(x, W_ih, W_hh, b_ih, b_hh, fc_w, fc_b, out);
}

// Round 3
// 221.504 us; speedup vs baseline: 1.3682x; 1.3682x over previous
//
#include <hip/hip_runtime.h>

#define T_LEN 1024

typedef _Float16 f16x8 __attribute__((ext_vector_type(8)));
typedef __fp16   fp16x2 __attribute__((ext_vector_type(2)));
typedef float    f32x4 __attribute__((ext_vector_type(4)));
typedef float    f32x2 __attribute__((ext_vector_type(2)));

// One wave (64 threads) per block; block owns 16 batch rows for all T steps.
// REGIME (established R0-R2): all 1024 waves are co-resident (1/SIMD); issue
// ports have slack (R1: +TLP didn't raise VALUBusy); the step body executes
// near-serially at dependency latency (R2: +40 VALU ops cost +114 cy/step,
// ~5 cy/op effective). Wall time = T x per-step chain. Only lever: fewer /
// cheaper instructions on the chain.
//   - trans count (8 exp + 8 rcp per lane) is minimal for any 16-row MFMA
//     tiling: 512 sigmoids / 64 lanes. HW trans kept (R2: software rcp lost).
//   - this round: halve scalar-VALU count via packed f32 (v_pk_fma_f32 for
//     C-init, v_pk_add_f32 for e+1) -- IEEE-identical per element.
//
// Recurrence in "r-space": h = 1 - 2r, r = 1/(exp2(t)+1), t = K*v, K = 2*log2(e).
//   t[c] = K*(x*Wih[c] + b[c] + rowsum(W_hh[c,:])) + sum_k (-2K*W_hh[c,k]) * r[k]
// A-frag = -2K*W_hh (f16); r recirculates directly as the B-fragment.
//   A-frag: A[m=lane&15][k=quad*8+j] = -2K*Whh[sigma(m)][k]
//   B-frag: B[k=quad*8+j][n=lane&15] = r[row n][k]
//   C-frag: col n=lane&15 (batch row), row m=quad*4+reg; sigma0(m)=8*(m>>2)+(m&3),
//   sigma1=sigma0+4 ==> lane's C outputs are exactly its own B slots next step.
__global__ __launch_bounds__(64) void rnn_fused(
    const float* __restrict__ x,      // [B, T]
    const float* __restrict__ W_ih,   // [32,1]
    const float* __restrict__ W_hh,   // [32,32]
    const float* __restrict__ b_ih,   // [32]
    const float* __restrict__ b_hh,   // [32]
    const float* __restrict__ fc_w,   // [1,32]
    const float* __restrict__ fc_b,   // [1]
    float* __restrict__ out)          // [B]
{
    const int lane = threadIdx.x;
    const int n = lane & 15;   // batch row within tile (B-frag col / C col)
    const int q = lane >> 4;   // quad index

    const float K = 2.88539008177792681472f;   // 2*log2(e)

    // A fragments: -2K * W_hh rows (permuted by sigma), f16.
    const int c0row = 8 * (n >> 2) + (n & 3);
    const int c1row = c0row + 4;
    f16x8 a0, a1;
#pragma unroll
    for (int j = 0; j < 8; ++j) {
        a0[j] = (_Float16)(-2.0f * K * W_hh[c0row * 32 + q * 8 + j]);
        a1[j] = (_Float16)(-2.0f * K * W_hh[c1row * 32 + q * 8 + j]);
    }

    // This lane produces h-columns c = 8q + i (i = 0..7), as f32x4 vectors so
    // the C-init compiles to v_pk_fma_f32 (packed, full rate, IEEE-identical).
    // bias' = K*(b_ih + b_hh + rowsum(W_hh[c,:]))  (r-space fold)
    f32x4 wv0, wv1, bv0, bv1;
#pragma unroll
    for (int i = 0; i < 8; ++i) {
        int c = 8 * q + i;
        float rs = 0.0f;
        for (int k = 0; k < 32; ++k) rs += W_hh[c * 32 + k];
        float wihc  = K * W_ih[c];
        float biasc = K * (b_ih[c] + b_hh[c] + rs);
        if (i < 4) { wv0[i] = wihc; bv0[i] = biasc; }
        else       { wv1[i - 4] = wihc; bv1[i - 4] = biasc; }
    }

    const float* xrow = x + (size_t)(blockIdx.x * 16 + n) * T_LEN;
    float4 xa = *(const float4*)xrow;   // t = 0..3 (4 lanes/row redundant -> broadcast)

    // B fragment holds r; h=0 <=> r=0.5
    f16x8 hb;
#pragma unroll
    for (int i = 0; i < 8; ++i) hb[i] = (_Float16)0.5f;

    for (int t4 = 0; t4 < T_LEN / 4; ++t4) {
        const int nt4 = (t4 < T_LEN / 4 - 1) ? t4 + 1 : t4;   // prefetch next x chunk
        float4 xn = *(const float4*)(xrow + (size_t)nt4 * 4);
#pragma unroll
        for (int p = 0; p < 4; ++p) {
            const float xt = (p == 0) ? xa.x : (p == 1) ? xa.y : (p == 2) ? xa.z : xa.w;
            const f32x4 xt4 = {xt, xt, xt, xt};
            // C-init = K*(x*Wih + b + rowsum): 2x v_pk_fma_f32 per acc
            f32x4 acc0 = __builtin_elementwise_fma(xt4, wv0, bv0);
            f32x4 acc1 = __builtin_elementwise_fma(xt4, wv1, bv1);
            acc0 = __builtin_amdgcn_mfma_f32_16x16x32_f16(a0, hb, acc0, 0, 0, 0);
            acc1 = __builtin_amdgcn_mfma_f32_16x16x32_f16(a1, hb, acc1, 0, 0, 0);

            // Pairwise epilogue: exp (HW trans) -> packed +1 (v_pk_add_f32)
            // -> HW rcp -> cvt_pkrtz. Fine-grained DAG so rcp stream starts
            // after the first exp pair, not after all 8.
            struct H4 { fp16x2 p[4]; } hh;

            f32x2 d0 = { __builtin_amdgcn_exp2f(acc0[0]),
                         __builtin_amdgcn_exp2f(acc0[1]) };
            d0 += 1.0f;
            hh.p[0] = __builtin_amdgcn_cvt_pkrtz(__builtin_amdgcn_rcpf(d0.x),
                                                 __builtin_amdgcn_rcpf(d0.y));

            f32x2 d1 = { __builtin_amdgcn_exp2f(acc0[2]),
                         __builtin_amdgcn_exp2f(acc0[3]) };
            d1 += 1.0f;
            hh.p[1] = __builtin_amdgcn_cvt_pkrtz(__builtin_amdgcn_rcpf(d1.x),
                                                 __builtin_amdgcn_rcpf(d1.y));

            f32x2 d2 = { __builtin_amdgcn_exp2f(acc1[0]),
                         __builtin_amdgcn_exp2f(acc1[1]) };
            d2 += 1.0f;
            hh.p[2] = __builtin_amdgcn_cvt_pkrtz(__builtin_amdgcn_rcpf(d2.x),
                                                 __builtin_amdgcn_rcpf(d2.y));

            f32x2 d3 = { __builtin_amdgcn_exp2f(acc1[2]),
                         __builtin_amdgcn_exp2f(acc1[3]) };
            d3 += 1.0f;
            hh.p[3] = __builtin_amdgcn_cvt_pkrtz(__builtin_amdgcn_rcpf(d3.x),
                                                 __builtin_amdgcn_rcpf(d3.y));

            hb = __builtin_bit_cast(f16x8, hh);
        }
        xa = xn;
    }

    // Head: h = 1 - 2r; out[row] = sum_c h[c] * fc_w[c] + fc_b
    float part = 0.0f;
#pragma unroll
    for (int i = 0; i < 8; ++i) {
        float h = fmaf(-2.0f, (float)hb[i], 1.0f);
        part = fmaf(h, fc_w[8 * q + i], part);
    }
    part += __shfl_xor(part, 16);
    part += __shfl_xor(part, 32);
    if (q == 0) out[blockIdx.x * 16 + n] = part + fc_b[0];
}

extern "C" void kernel_launch(void* const* d_in, const int* in_sizes, int n_in,
                              void* d_out, int out_size, void* d_ws, size_t ws_size,
                              hipStream_t stream) {
    const float* x    = (const float*)d_in[0];
    const float* W_ih = (const float*)d_in[1];
    const float* W_hh = (const float*)d_in[2];
    const float* b_ih = (const float*)d_in[3];
    const float* b_hh = (const float*)d_in[4];
    const float* fc_w = (const float*)d_in[5];
    const float* fc_b = (const float*)d_in[6];
    float* out = (float*)d_out;

    const int B = in_sizes[0] / T_LEN;   // 16384
    rnn_fused<<<B / 16, 64, 0, stream>>>(x, W_ih, W_hh, b_ih, b_hh, fc_w, fc_b, out);
}